// Round 1
// baseline (67.880 us; speedup 1.0000x reference)
//
#include <hip/hip_runtime.h>

// NMS2d, x: (8,16,512,512) f32. out = x * (x > max of 8 neighbors, replicate pad).
// Memory-bound: 134MB read + 134MB write => ~43us floor at 6.3 TB/s.

#define IMG_H 512
#define IMG_W 512
#define W4 (IMG_W / 4)   // 128 float4 groups per row

__global__ __launch_bounds__(256) void nms2d_kernel(const float* __restrict__ x,
                                                    float* __restrict__ out,
                                                    int total4) {
    int tid = blockIdx.x * blockDim.x + threadIdx.x;
    if (tid >= total4) return;

    // tid -> (bc, y, wx); wx fastest so tid*4 is the linear element index
    int wx   = tid & (W4 - 1);
    int rest = tid >> 7;           // / W4
    int y    = rest & (IMG_H - 1);
    int bc   = rest >> 9;          // / IMG_H

    const float* img = x + (size_t)bc * IMG_H * IMG_W;
    int col = wx << 2;
    int ym = (y > 0) ? y - 1 : 0;             // replicate pad
    int yp = (y < IMG_H - 1) ? y + 1 : IMG_H - 1;

    const float4 cm = *(const float4*)(img + (size_t)ym * IMG_W + col);
    const float4 cc = *(const float4*)(img + (size_t)y  * IMG_W + col);
    const float4 cp = *(const float4*)(img + (size_t)yp * IMG_W + col);

    float lm, lc, lp, rm, rc, rp;
    if (wx > 0) {
        lm = img[(size_t)ym * IMG_W + col - 1];
        lc = img[(size_t)y  * IMG_W + col - 1];
        lp = img[(size_t)yp * IMG_W + col - 1];
    } else {            // replicate: left neighbor of col 0 is col 0 itself
        lm = cm.x; lc = cc.x; lp = cp.x;
    }
    if (wx < W4 - 1) {
        rm = img[(size_t)ym * IMG_W + col + 4];
        rc = img[(size_t)y  * IMG_W + col + 4];
        rp = img[(size_t)yp * IMG_W + col + 4];
    } else {            // replicate: right neighbor of col W-1 is col W-1 itself
        rm = cm.w; rc = cc.w; rp = cp.w;
    }

    // 6-wide windows per row (static-indexed after unroll -> registers)
    float vm[6] = {lm, cm.x, cm.y, cm.z, cm.w, rm};
    float vc[6] = {lc, cc.x, cc.y, cc.z, cc.w, rc};
    float vp[6] = {lp, cp.x, cp.y, cp.z, cp.w, rp};

    float4 o;
    float* op = &o.x;
#pragma unroll
    for (int k = 0; k < 4; ++k) {
        float m = fmaxf(fmaxf(vm[k], vm[k + 1]), vm[k + 2]);   // top row (3)
        m = fmaxf(m, fmaxf(vc[k], vc[k + 2]));                 // mid row, skip center (2)
        m = fmaxf(m, fmaxf(fmaxf(vp[k], vp[k + 1]), vp[k + 2])); // bottom row (3)
        float c = vc[k + 1];
        op[k] = (c > m) ? c : 0.0f;
    }

    *(float4*)(out + (size_t)tid * 4) = o;
}

extern "C" void kernel_launch(void* const* d_in, const int* in_sizes, int n_in,
                              void* d_out, int out_size, void* d_ws, size_t ws_size,
                              hipStream_t stream) {
    const float* x = (const float*)d_in[0];
    float* out = (float*)d_out;
    int total4 = in_sizes[0] / 4;            // 8*16*512*512 / 4 = 8,388,608
    int block = 256;
    int grid = (total4 + block - 1) / block; // 32768 blocks
    nms2d_kernel<<<grid, block, 0, stream>>>(x, out, total4);
}

// Round 2
// 52.028 us; speedup vs baseline: 1.3047x; 1.3047x over previous
//
#include <hip/hip_runtime.h>

// NMS2d, x: (8,16,512,512) f32. out = x where x > max of 8 neighbors (replicate pad).
// Round 2: 2 output rows per thread, halo columns via __shfl instead of scalar
// loads. VMEM instrs per 8 pixels: 4 float4 loads + 2 float4 stores (was 6
// loads + 12 scalar halos + 2 stores).

#define IMG_H 512
#define IMG_W 512
#define W4 (IMG_W / 4)   // 128 float4 groups per row

__global__ __launch_bounds__(256) void nms2d_kernel(const float* __restrict__ x,
                                                    float* __restrict__ out,
                                                    int total) {
    int tid = blockIdx.x * blockDim.x + threadIdx.x;
    if (tid >= total) return;

    // tid -> (bc, yt, wx); wx fastest. Each thread: rows y0=2*yt, y0+1, cols 4*wx..4*wx+3.
    int wx   = tid & (W4 - 1);
    int rest = tid >> 7;
    int yt   = rest & 255;          // 256 row-pairs per image
    int bc   = rest >> 8;
    int y0   = yt << 1;

    const float* img  = x   + (size_t)bc * (IMG_H * IMG_W);
    float*       oimg = out + (size_t)bc * (IMG_H * IMG_W);
    int col = wx << 2;

    int rT = (y0 > 0) ? y0 - 1 : 0;                 // replicate pad rows
    int rB = (y0 + 2 < IMG_H) ? y0 + 2 : IMG_H - 1;
    int ridx[4] = {rT, y0, y0 + 1, rB};

    float4 rows[4];
    rows[0] = *(const float4*)(img + (size_t)rT       * IMG_W + col);
    rows[1] = *(const float4*)(img + (size_t)y0       * IMG_W + col);
    rows[2] = *(const float4*)(img + (size_t)(y0 + 1) * IMG_W + col);
    rows[3] = *(const float4*)(img + (size_t)rB       * IMG_W + col);

    int lane = threadIdx.x & 63;
    // Within a wave, wx is 64 consecutive values (0..63 or 64..127), same yt/bc.
    bool waveL = (lane == 0);    // left halo not in this wave
    bool waveR = (lane == 63);   // right halo not in this wave

    float L[4], R[4];
#pragma unroll
    for (int r = 0; r < 4; ++r) {
        float lv = __shfl_up(rows[r].w, 1);
        float rv = __shfl_down(rows[r].x, 1);
        if (waveL) {
            lv = (wx == 0) ? rows[r].x
                           : img[(size_t)ridx[r] * IMG_W + col - 1];
        }
        if (waveR) {
            rv = (wx == W4 - 1) ? rows[r].w
                                : img[(size_t)ridx[r] * IMG_W + col + 4];
        }
        L[r] = lv;
        R[r] = rv;
    }

    // 6-wide windows per row (fully unrolled -> registers)
    float v[4][6];
#pragma unroll
    for (int r = 0; r < 4; ++r) {
        v[r][0] = L[r];
        v[r][1] = rows[r].x; v[r][2] = rows[r].y;
        v[r][3] = rows[r].z; v[r][4] = rows[r].w;
        v[r][5] = R[r];
    }

    // horizontal max-of-3 per row
    float h3[4][4];
#pragma unroll
    for (int r = 0; r < 4; ++r)
#pragma unroll
        for (int k = 0; k < 4; ++k)
            h3[r][k] = fmaxf(fmaxf(v[r][k], v[r][k + 1]), v[r][k + 2]);

    float4 o0, o1;
    float* o0p = &o0.x;
    float* o1p = &o1.x;
#pragma unroll
    for (int k = 0; k < 4; ++k) {
        // output row y0: rows 0(top),1(center),2(bottom)
        float m0 = fmaxf(fmaxf(h3[0][k], h3[2][k]), fmaxf(v[1][k], v[1][k + 2]));
        float c0 = v[1][k + 1];
        o0p[k] = (c0 > m0) ? c0 : 0.0f;
        // output row y0+1: rows 1(top),2(center),3(bottom)
        float m1 = fmaxf(fmaxf(h3[1][k], h3[3][k]), fmaxf(v[2][k], v[2][k + 2]));
        float c1 = v[2][k + 1];
        o1p[k] = (c1 > m1) ? c1 : 0.0f;
    }

    *(float4*)(oimg + (size_t)y0       * IMG_W + col) = o0;
    *(float4*)(oimg + (size_t)(y0 + 1) * IMG_W + col) = o1;
}

extern "C" void kernel_launch(void* const* d_in, const int* in_sizes, int n_in,
                              void* d_out, int out_size, void* d_ws, size_t ws_size,
                              hipStream_t stream) {
    const float* x = (const float*)d_in[0];
    float* out = (float*)d_out;
    int total = in_sizes[0] / 8;             // threads: 8 px each = 4,194,304
    int block = 256;
    int grid = (total + block - 1) / block;  // 16384 blocks
    nms2d_kernel<<<grid, block, 0, stream>>>(x, out, total);
}

// Round 4
// 46.901 us; speedup vs baseline: 1.4473x; 1.1093x over previous
//
#include <hip/hip_runtime.h>

// NMS2d, x: (8,16,512,512) f32. out = x where x > max of 8 neighbors (replicate pad).
// Round 4: same as round 3 (4 rows x 4 cols per thread, shfl halos, nontemporal
// output stores) but with clang ext_vector_type so __builtin_nontemporal_store
// compiles.

#define IMG_H 512
#define IMG_W 512
#define W4 (IMG_W / 4)   // 128 float4 groups per row
#define RPT 4            // rows per thread

typedef float f4 __attribute__((ext_vector_type(4)));

__global__ __launch_bounds__(256) void nms2d_kernel(const float* __restrict__ x,
                                                    float* __restrict__ out,
                                                    int total) {
    int tid = blockIdx.x * blockDim.x + threadIdx.x;
    if (tid >= total) return;

    // tid -> (bc, yt, wx); wx fastest. Rows y0..y0+3, cols 4*wx..4*wx+3.
    int wx   = tid & (W4 - 1);
    int rest = tid >> 7;
    int yt   = rest & (IMG_H / RPT - 1);   // 128 row-quads per image
    int bc   = rest >> 7;
    int y0   = yt << 2;

    const float* img  = x   + (size_t)bc * (IMG_H * IMG_W);
    float*       oimg = out + (size_t)bc * (IMG_H * IMG_W);
    int col = wx << 2;

    int rT = (y0 > 0) ? y0 - 1 : 0;                   // replicate pad rows
    int rB = (y0 + RPT < IMG_H) ? y0 + RPT : IMG_H - 1;
    int ridx[6] = {rT, y0, y0 + 1, y0 + 2, y0 + 3, rB};

    f4 rows[6];
#pragma unroll
    for (int r = 0; r < 6; ++r)
        rows[r] = *(const f4*)(img + (size_t)ridx[r] * IMG_W + col);

    int lane = threadIdx.x & 63;
    bool waveL = (lane == 0);    // left halo not in this wave
    bool waveR = (lane == 63);   // right halo not in this wave

    // 6-wide windows per row: [L, x0, x1, x2, x3, R]
    float v[6][6];
#pragma unroll
    for (int r = 0; r < 6; ++r) {
        float lv = __shfl_up(rows[r].w, 1);
        float rv = __shfl_down(rows[r].x, 1);
        if (waveL)
            lv = (wx == 0) ? rows[r].x : img[(size_t)ridx[r] * IMG_W + col - 1];
        if (waveR)
            rv = (wx == W4 - 1) ? rows[r].w : img[(size_t)ridx[r] * IMG_W + col + 4];
        v[r][0] = lv;
        v[r][1] = rows[r].x; v[r][2] = rows[r].y;
        v[r][3] = rows[r].z; v[r][4] = rows[r].w;
        v[r][5] = rv;
    }

    // horizontal max-of-3 per row
    float h3[6][4];
#pragma unroll
    for (int r = 0; r < 6; ++r)
#pragma unroll
        for (int k = 0; k < 4; ++k)
            h3[r][k] = fmaxf(fmaxf(v[r][k], v[r][k + 1]), v[r][k + 2]);

    // output rows: centers are v[1..4]; top/bottom h3 of r-1, r+1
#pragma unroll
    for (int r = 1; r <= RPT; ++r) {
        f4 o;
#pragma unroll
        for (int k = 0; k < 4; ++k) {
            float m = fmaxf(fmaxf(h3[r - 1][k], h3[r + 1][k]),
                            fmaxf(v[r][k], v[r][k + 2]));
            float c = v[r][k + 1];
            o[k] = (c > m) ? c : 0.0f;
        }
        __builtin_nontemporal_store(o,
            (f4*)(oimg + (size_t)(y0 + r - 1) * IMG_W + col));
    }
}

extern "C" void kernel_launch(void* const* d_in, const int* in_sizes, int n_in,
                              void* d_out, int out_size, void* d_ws, size_t ws_size,
                              hipStream_t stream) {
    const float* x = (const float*)d_in[0];
    float* out = (float*)d_out;
    int total = in_sizes[0] / 16;            // 16 px per thread = 2,097,152
    int block = 256;
    int grid = (total + block - 1) / block;  // 8192 blocks
    nms2d_kernel<<<grid, block, 0, stream>>>(x, out, total);
}

// Round 5
// 45.598 us; speedup vs baseline: 1.4887x; 1.0286x over previous
//
#include <hip/hip_runtime.h>

// NMS2d, x: (8,16,512,512) f32. out = x where x > max of 8 neighbors (replicate pad).
// Round 5: 8 output rows x 4 cols per thread (32 px). 10 float4 loads + 8
// nontemporal float4 stores per thread. Halo columns via __shfl.

#define IMG_H 512
#define IMG_W 512
#define W4 (IMG_W / 4)   // 128 float4 groups per row
#define RPT 8            // rows per thread
#define NR (RPT + 2)     // loaded rows incl. top/bottom halo

typedef float f4 __attribute__((ext_vector_type(4)));

__global__ __launch_bounds__(256) void nms2d_kernel(const float* __restrict__ x,
                                                    float* __restrict__ out,
                                                    int total) {
    int tid = blockIdx.x * blockDim.x + threadIdx.x;
    if (tid >= total) return;

    // tid -> (bc, yt, wx); wx fastest. Rows y0..y0+7, cols 4*wx..4*wx+3.
    int wx   = tid & (W4 - 1);
    int rest = tid >> 7;
    int yt   = rest & (IMG_H / RPT - 1);   // 64 row-octets per image
    int bc   = rest >> 6;
    int y0   = yt << 3;

    const float* img  = x   + (size_t)bc * (IMG_H * IMG_W);
    float*       oimg = out + (size_t)bc * (IMG_H * IMG_W);
    int col = wx << 2;

    int ridx[NR];
    ridx[0] = (y0 > 0) ? y0 - 1 : 0;                         // replicate pad
#pragma unroll
    for (int r = 1; r <= RPT; ++r) ridx[r] = y0 + r - 1;
    ridx[NR - 1] = (y0 + RPT < IMG_H) ? y0 + RPT : IMG_H - 1;

    f4 rows[NR];
#pragma unroll
    for (int r = 0; r < NR; ++r)
        rows[r] = *(const f4*)(img + (size_t)ridx[r] * IMG_W + col);

    int lane = threadIdx.x & 63;
    bool waveL = (lane == 0);    // left halo not in this wave
    bool waveR = (lane == 63);   // right halo not in this wave

    // 6-wide windows per row: [L, x0, x1, x2, x3, R]
    float v[NR][6];
#pragma unroll
    for (int r = 0; r < NR; ++r) {
        float lv = __shfl_up(rows[r].w, 1);
        float rv = __shfl_down(rows[r].x, 1);
        if (waveL)
            lv = (wx == 0) ? rows[r].x : img[(size_t)ridx[r] * IMG_W + col - 1];
        if (waveR)
            rv = (wx == W4 - 1) ? rows[r].w : img[(size_t)ridx[r] * IMG_W + col + 4];
        v[r][0] = lv;
        v[r][1] = rows[r].x; v[r][2] = rows[r].y;
        v[r][3] = rows[r].z; v[r][4] = rows[r].w;
        v[r][5] = rv;
    }

    // horizontal max-of-3 per row
    float h3[NR][4];
#pragma unroll
    for (int r = 0; r < NR; ++r)
#pragma unroll
        for (int k = 0; k < 4; ++k)
            h3[r][k] = fmaxf(fmaxf(v[r][k], v[r][k + 1]), v[r][k + 2]);

    // output rows: centers are v[1..RPT]; top/bottom h3 of r-1, r+1
#pragma unroll
    for (int r = 1; r <= RPT; ++r) {
        f4 o;
#pragma unroll
        for (int k = 0; k < 4; ++k) {
            float m = fmaxf(fmaxf(h3[r - 1][k], h3[r + 1][k]),
                            fmaxf(v[r][k], v[r][k + 2]));
            float c = v[r][k + 1];
            o[k] = (c > m) ? c : 0.0f;
        }
        __builtin_nontemporal_store(o,
            (f4*)(oimg + (size_t)(y0 + r - 1) * IMG_W + col));
    }
}

extern "C" void kernel_launch(void* const* d_in, const int* in_sizes, int n_in,
                              void* d_out, int out_size, void* d_ws, size_t ws_size,
                              hipStream_t stream) {
    const float* x = (const float*)d_in[0];
    float* out = (float*)d_out;
    int total = in_sizes[0] / (4 * RPT);     // 32 px per thread = 524,288
    int block = 256;
    int grid = (total + block - 1) / block;  // 2048 blocks
    nms2d_kernel<<<grid, block, 0, stream>>>(x, out, total);
}